// Round 8
// baseline (883.789 us; speedup 1.0000x reference)
//
#include <hip/hip_runtime.h>

// ---------------------------------------------------------------------------
// VQ layer: N=32768 latents, K=8192 prototypes, D=512 (fp32 in/out).
// out[0..N*D) = prototypes[argmin_k ||x_n - p_k||^2];  out[N*D] = 1.25*mean((q-x)^2)
//
// R15: m201-geometry port (the HW-proven 256^2 8-wave template), replacing my
// custom geometries that kept landing in allocator dead zones (R8-R14 spills).
//   - 512 threads = 8 waves (4M x 2N), tile 256x256, wave owns 64x128.
//     A 512-thr block FORCES the compiler to plan 2 waves/SIMD -> unified
//     budget exactly 256/wave; demand ~230 (acc 128 AGPR + arch ~100) fits —
//     the HK/m201 operating point, proven spill-free in plain HIP.
//   - 2-buffer A+B LDS (2 x 64KB) + pnC 4KB = 132KB, 1 block/CU, 8 waves/CU.
//   - Counted-vmcnt single-barrier schedule (logic proven R8-R13, absmax
//     identical): per step { s_barrier; stage(s+1 -> buf^1); vmcnt(8)
//     [retires stage-s, keeps stage-s+1 in flight under compute];
//     sched_barrier; 24 ds_read_b128 + 32 MFMA (setprio) }. Barrier-at-top
//     protects buf^1 writes vs step-s-1 readers (their MFMA consumption
//     forces lgkm retirement before they reach the barrier). vmcnt(0) only
//     at the last step.
//   - Per-CU step: MFMA 2208 SIMD-cy vs LDS 2304+~770 -> LDS-bound ~70% cap.
// Same XOR-swizzled 16B-chunk layout (0 bank conflicts), same MX-scaled
// mfma_scale_f32_16x16x128_f8f6f4 (scale=127 -> x1.0), same k-map as R7.
// ---------------------------------------------------------------------------

#define N_ROWS 32768
#define K_PROTO 8192
#define DIM 512              // bytes per row in fp8 == elements
#define BM 256               // rows per block
#define BN 256               // cols per tile
#define BKB 128              // K-bytes per slice = one K=128 MFMA
#define GROUPS 8
#define TILES 4              // GROUPS * TILES * BN == K_PROTO
#define NSTEP 16             // TILES * (DIM/BKB) slices
#define HBUF 32768           // bytes per half (A or B) per buffer

typedef unsigned char u8;
typedef unsigned int u32;
typedef __attribute__((ext_vector_type(4))) int i32x4;        // 16B LDS chunk
typedef __attribute__((ext_vector_type(8))) int i32x8;        // 32B MFMA A/B frag
typedef __attribute__((ext_vector_type(4))) float f32x4;      // MFMA C/D frag

__device__ __forceinline__ void async16(const void* g, void* s) {
    __builtin_amdgcn_global_load_lds(
        (const __attribute__((address_space(1))) void*)g,
        (__attribute__((address_space(3))) void*)s, 16, 0, 0);
}

// pack 4 floats -> 4 fp8 e4m3 bytes (HW RNE, saturating)
__device__ __forceinline__ int pk4(float a, float b, float c, float d) {
    int v = 0;
    v = __builtin_amdgcn_cvt_pk_fp8_f32(a, b, v, false);   // bytes 0,1
    v = __builtin_amdgcn_cvt_pk_fp8_f32(c, d, v, true);    // bytes 2,3
    return v;
}

// ---------------------------------------------------------------------------
// latents fp32 -> fp8, 16 elems/thread. grid 4096 x 256. blocks 0..127 also
// init best[].
__global__ void __launch_bounds__(256) conv_latents(const float* __restrict__ X,
                                                    u8* __restrict__ Xf,
                                                    u32* __restrict__ best) {
    if (blockIdx.x < 128) best[blockIdx.x * 256 + threadIdx.x] = 0xFFFFFFFFu;
    size_t i = ((size_t)blockIdx.x * 256 + threadIdx.x) * 16;
    float4 a = ((const float4*)(X + i))[0];
    float4 b = ((const float4*)(X + i))[1];
    float4 c = ((const float4*)(X + i))[2];
    float4 d = ((const float4*)(X + i))[3];
    int4 o;
    o.x = pk4(a.x, a.y, a.z, a.w);
    o.y = pk4(b.x, b.y, b.z, b.w);
    o.z = pk4(c.x, c.y, c.z, c.w);
    o.w = pk4(d.x, d.y, d.z, d.w);
    *(int4*)(Xf + i) = o;
}

// protos fp32 -> fp8 (x8192; raw p ~1e-4 would be denormal) + pnC[k] =
// 8192*||p||^2 + 256 (positive scaled scores -> bit-monotone u32 key).
__global__ void __launch_bounds__(256) conv_protos(const float* __restrict__ P,
                                                   u8* __restrict__ Pf,
                                                   float* __restrict__ pnC) {
    int row  = blockIdx.x * 4 + (threadIdx.x >> 6);
    int lane = threadIdx.x & 63;
    const float* src = P + (size_t)row * DIM + lane * 8;
    float4 a = ((const float4*)src)[0];
    float4 b = ((const float4*)src)[1];
    int2 o;
    o.x = pk4(a.x * 8192.0f, a.y * 8192.0f, a.z * 8192.0f, a.w * 8192.0f);
    o.y = pk4(b.x * 8192.0f, b.y * 8192.0f, b.z * 8192.0f, b.w * 8192.0f);
    *(int2*)(Pf + (size_t)row * DIM + lane * 8) = o;
    float ss = a.x*a.x + a.y*a.y + a.z*a.z + a.w*a.w
             + b.x*b.x + b.y*b.y + b.z*b.z + b.w*b.w;
    #pragma unroll
    for (int off = 32; off; off >>= 1) ss += __shfl_down(ss, off);
    if (lane == 0) pnC[row] = ss * 8192.0f + 256.0f;
}

// ---------------------------------------------------------------------------
// Score: block = 256 rows x (TILES=4 x 256) cols; 8 waves (4M x 2N), wave
// (wm,wn) owns rows [wm*64,+64) x cols [wn*128,+128). A+B double-buffered in
// LDS, counted-vmcnt single-barrier pipeline.
// ---------------------------------------------------------------------------
__global__ void __launch_bounds__(512, 1) vq_score_kernel(const u8* __restrict__ Xf,
                                                          const u8* __restrict__ Pf,
                                                          const float* __restrict__ pnC,
                                                          u32* __restrict__ best) {
    // [buf0: A 32KB | B 32KB][buf1: A 32KB | B 32KB][pcs 4KB] = 132KB
    __shared__ __align__(16) u8 lds_raw[4 * HBUF + 4096];
    float* pcs = (float*)(lds_raw + 4 * HBUF);

    const int tid  = threadIdx.x;
    const int row0 = blockIdx.x * BM;
    const int colg = blockIdx.y * (TILES * BN);

    const int w    = tid >> 6, lane = tid & 63;
    const int wm   = w >> 1,  wn   = w & 1;
    const int quad = lane >> 4, l15 = lane & 15;

    // staging map: A-slice (256 rows x 128B) = 2048 16B chunks; thread t
    // handles chunks f = t + i*512 (i<4). Global chunk c = (f&7) ^ (row&7);
    // LINEAR LDS position (f&7) holds the swizzled chunk (pre-swizzled-source;
    // global_load_lds dest must be linear). Same map for B.
    int voff[4];
    #pragma unroll
    for (int i = 0; i < 4; i++) {
        int f = tid + i * 512;
        int row = f >> 3, c = (f & 7) ^ (row & 7);
        voff[i] = row * DIM + c * 16;
    }

    // k-map: lane quad q consumes global chunks q (frag bytes 0..15) and q|4
    // (bytes 16..31) of its row; swizzled LDS pos = (q ^ (l15&7))*16.
    const int x7   = l15 & 7;
    const int pos0 = (quad ^ x7) << 4;
    const int pos1 = pos0 ^ 64;

    // ---- prologue: stage slice 0 -> buf0, pnC -> LDS, stage slice 1 -> buf1.
    {
        const u8* As = Xf + (size_t)row0 * DIM;
        const u8* Bsrc = Pf + (size_t)colg * DIM;
        #pragma unroll
        for (int i = 0; i < 4; i++) {                       // slice 0, buf 0
            async16(As + voff[i], lds_raw + tid * 16 + i * 8192);
            async16(Bsrc + voff[i], lds_raw + HBUF + tid * 16 + i * 8192);
        }
        if (tid < 256)                                       // 4KB pnC
            async16((const u8*)(pnC + colg) + tid * 16,
                    lds_raw + 4 * HBUF + tid * 16);
        #pragma unroll
        for (int i = 0; i < 4; i++) {                       // slice 1, buf 1
            async16(As + voff[i] + 1 * BKB, lds_raw + 2 * HBUF + tid * 16 + i * 8192);
            async16(Bsrc + voff[i] + 1 * BKB, lds_raw + 3 * HBUF + tid * 16 + i * 8192);
        }
    }

    u32 v[4][4];
    #pragma unroll
    for (int i = 0; i < 4; i++)
        #pragma unroll
        for (int r = 0; r < 4; r++) v[i][r] = 0xFFFFFFFFu;

    // ---- main loop: 4 tiles x 4 slices = 16 steps.
    // Step s: barrier (step s-1 readers of buf^1 are done) -> stage s+1 into
    // buf^1 -> vmcnt(8) (retires stage-s [+pnC at s=0]; stage-s+1 stays in
    // flight under the compute) -> ds_read+MFMA from buf s&1.
    for (int t = 0; t < TILES; ++t) {
        f32x4 acc[4][8];
        #pragma unroll
        for (int i = 0; i < 4; i++)
            #pragma unroll
            for (int j = 0; j < 8; j++) acc[i][j] = (f32x4)0.0f;

        #pragma unroll
        for (int kt = 0; kt < 4; ++kt) {
            const int s = t * 4 + kt;
            __builtin_amdgcn_s_barrier();

            if (s > 0 && s + 1 < NSTEP) {      // stage slice s+1 into buf^1
                const int s2 = s + 1;
                const int kt2 = s2 & 3;
                u8* dA = lds_raw + ((s2 & 1) ? 2 * HBUF : 0);
                u8* dB = dA + HBUF;
                const u8* As = Xf + (size_t)row0 * DIM + kt2 * BKB;
                const u8* Bsrc = Pf + (size_t)(colg + (s2 >> 2) * BN) * DIM + kt2 * BKB;
                #pragma unroll
                for (int i = 0; i < 4; i++) {
                    async16(As + voff[i], dA + tid * 16 + i * 8192);
                    async16(Bsrc + voff[i], dB + tid * 16 + i * 8192);
                }
            }
            if (s == NSTEP - 1)
                asm volatile("s_waitcnt vmcnt(0)" ::: "memory");
            else
                asm volatile("s_waitcnt vmcnt(8)" ::: "memory");
            __builtin_amdgcn_sched_barrier(0);   // compute strictly after wait

            const u8* Ab = lds_raw + ((s & 1) ? 2 * HBUF : 0);
            const u8* Bb = Ab + HBUF;

            // A fragments for this wave's 4 m-tiles (rows wm*64+tm*16+l15)
            i32x8 af[4];
            #pragma unroll
            for (int tm = 0; tm < 4; tm++) {
                const u8* p = Ab + (wm * 64 + tm * 16 + l15) * BKB;
                af[tm] = __builtin_shufflevector(*(const i32x4*)(p + pos0),
                                                 *(const i32x4*)(p + pos1),
                                                 0, 1, 2, 3, 4, 5, 6, 7);
            }
            __builtin_amdgcn_s_setprio(1);
            #pragma unroll
            for (int tn = 0; tn < 8; tn++) {
                const u8* bp = Bb + (wn * 128 + tn * 16 + l15) * BKB;
                i32x8 b = __builtin_shufflevector(
                    *(const i32x4*)(bp + pos0), *(const i32x4*)(bp + pos1),
                    0, 1, 2, 3, 4, 5, 6, 7);
                // fmtA=0 (fp8 e4m3), fmtB=0, scales 127 -> 2^0
                #pragma unroll
                for (int tm = 0; tm < 4; tm++)
                    acc[tm][tn] = __builtin_amdgcn_mfma_scale_f32_16x16x128_f8f6f4(
                        af[tm], b, acc[tm][tn], 0, 0, 0, 127, 0, 127);
            }
            __builtin_amdgcn_s_setprio(0);
            __builtin_amdgcn_sched_barrier(0);
        }

        // fold tile into register argmin; pc from LDS (stable since prologue).
        // C/D layout: col = l15 (+wn*128+tn*16), row = quad*4+r (+wm*64+tm*16).
        #pragma unroll
        for (int tn = 0; tn < 8; tn++) {
            const int ci = t * BN + wn * 128 + tn * 16 + l15;
            const float pc = pcs[ci];
            const u32 kidx = (u32)(colg + ci);
            #pragma unroll
            for (int tm = 0; tm < 4; tm++)
                #pragma unroll
                for (int r = 0; r < 4; r++) {
                    float sk = fmaf(-2.0f, acc[tm][tn][r], pc);
                    u32 key = (__float_as_uint(sk) & 0xFFFFE000u) | kidx;
                    if (key < v[tm][r]) v[tm][r] = key;
                }
        }
    }

    // quad-local xor-reduce over the 16 l15 lanes (cols); one writer lane per
    // row -> direct global atomicMin.
    #pragma unroll
    for (int tm = 0; tm < 4; tm++)
        #pragma unroll
        for (int r = 0; r < 4; r++) {
            u32 x = v[tm][r];
            #pragma unroll
            for (int off = 1; off < 16; off <<= 1) {
                u32 o = (u32)__shfl_xor((int)x, off);
                if (o < x) x = o;
            }
            if (l15 == 0)
                atomicMin(&best[row0 + wm * 64 + tm * 16 + quad * 4 + r], x);
        }
}

// ---------------------------------------------------------------------------
// Gather chosen prototype (original fp32) + per-row loss partial (NO atomics).
__global__ void __launch_bounds__(128) vq_gather_kernel(const float* __restrict__ X,
                                                        const float* __restrict__ P,
                                                        const u32* __restrict__ best,
                                                        float* __restrict__ out,
                                                        float* __restrict__ partial) {
    const int n = blockIdx.x, t = threadIdx.x;
    const u32 k = best[n] & (K_PROTO - 1);
    const float4 p = ((const float4*)(P + (size_t)k * DIM))[t];
    const float4 x = ((const float4*)(X + (size_t)n * DIM))[t];
    ((float4*)(out + (size_t)n * DIM))[t] = p;
    float dx = p.x - x.x, dy = p.y - x.y, dz = p.z - x.z, dw = p.w - x.w;
    float ss = dx * dx + dy * dy + dz * dz + dw * dw;
    #pragma unroll
    for (int off = 32; off; off >>= 1) ss += __shfl_down(ss, off);
    __shared__ float part[2];
    if ((t & 63) == 0) part[t >> 6] = ss;
    __syncthreads();
    if (t == 0) partial[n] = part[0] + part[1];
}

// single-block final loss reduction: 32768 partials -> out[N*D].
__global__ void __launch_bounds__(256) loss_reduce(const float* __restrict__ partial,
                                                   float* __restrict__ out) {
    const int t = threadIdx.x;
    float s = 0.0f;
    #pragma unroll
    for (int i = 0; i < 32; i++) {            // 256 thr x 32 float4 = 32768
        float4 a = ((const float4*)partial)[t * 32 + i];
        s += a.x + a.y + a.z + a.w;
    }
    #pragma unroll
    for (int off = 32; off; off >>= 1) s += __shfl_down(s, off);
    __shared__ float part[4];
    if ((t & 63) == 0) part[t >> 6] = s;
    __syncthreads();
    if (t == 0)
        out[(size_t)N_ROWS * DIM] =
            (part[0] + part[1] + part[2] + part[3]) * 7.450580596923828e-08f; // 1.25/(N*D)
}

// ---------------------------------------------------------------------------
extern "C" void kernel_launch(void* const* d_in, const int* in_sizes, int n_in,
                              void* d_out, int out_size, void* d_ws, size_t ws_size,
                              hipStream_t stream) {
    const float* X = (const float*)d_in[0];   // latents  [32768,512] fp32
    const float* P = (const float*)d_in[1];   // protos   [8192,512]  fp32
    float* out = (float*)d_out;
    char* ws = (char*)d_ws;

    // ws: Xf 16MB | Pf 4MB | pnC 32KB | best(u32) 128KB | partial 128KB
    u8* Xf = (u8*)ws;
    u8* Pf = (u8*)(ws + 16777216);
    float* pnC = (float*)(ws + 20971520);
    u32* best = (u32*)(ws + 21004288);
    float* partial = (float*)(ws + 21135360);

    conv_latents<<<dim3(4096), dim3(256), 0, stream>>>(X, Xf, best);
    conv_protos<<<dim3(2048), dim3(256), 0, stream>>>(P, Pf, pnC);
    vq_score_kernel<<<dim3(N_ROWS / BM, GROUPS), dim3(512), 0, stream>>>(Xf, Pf, pnC, best);
    vq_gather_kernel<<<dim3(N_ROWS), dim3(128), 0, stream>>>(X, P, best, out, partial);
    loss_reduce<<<dim3(1), dim3(256), 0, stream>>>(partial, out);
}